// Round 7
// baseline (28.642 us; speedup 1.0000x reference)
//
#include <hip/hip_runtime.h>

#define NQ 8
#define NL 4
#define NO 16  // = 2*NQ output features

typedef __attribute__((ext_vector_type(4))) float float4v;

__global__ __launch_bounds__(256) void qcl_fused(
    const float* __restrict__ x,    // [B,S,64] f32
    const float* __restrict__ rot,  // [NL,NQ,3] f32
    const float* __restrict__ ent,  // [NL,NQ-1] f32
    const float* __restrict__ pw,   // [NO,NQ] f32
    const float* __restrict__ pb,   // [NO] f32
    float* __restrict__ out,        // [B,S,NO] f32
    int n_rows)
{
    __shared__ float sScale[NL][NQ];     // (cos+sin)^3 per (layer,qubit)
    __shared__ float sWl[NL][NQ - 1];    // sigmoid(entangle)
    __shared__ float sW[NO][NQ];         // composed W_eff, row-major 32B rows
    __shared__ float sB[NO];

    const int tid = threadIdx.x;

    // ---- issue all 4 strided global loads FIRST; prologue hides latency ----
    const int nhalf = n_rows * 2;
    const int H = gridDim.x * 256;       // 262144 threads; 4 half-rows each
    const int gid = blockIdx.x * 256 + tid;
    const int h = tid & 1;               // pair parity (same for all 4)

    int g[4];
    bool v[4];
    #pragma unroll
    for (int k = 0; k < 4; ++k) { g[k] = gid + k * H; v[k] = g[k] < nhalf; }

    float4v a[4];
    #pragma unroll
    for (int k = 0; k < 4; ++k) {
        a[k] = float4v{0.f, 0.f, 0.f, 0.f};
        if (v[k]) a[k] = *(const float4v*)(x + (size_t)(g[k] >> 1) * 64 + h * 4);
    }

    // ---- distributed prologue: trans ops spread across 60 threads ----
    if (tid < NL * NQ) {                       // 32 threads: one scale each
        const int l = tid >> 3, q = tid & 7;
        const float r0 = rot[(l * NQ + q) * 3 + 0];
        const float r1 = rot[(l * NQ + q) * 3 + 1];
        const float r2 = rot[(l * NQ + q) * 3 + 2];
        sScale[l][q] = (__cosf(r0) + __sinf(r0)) *
                       (__cosf(r1) + __sinf(r1)) *
                       (__cosf(r2) + __sinf(r2));
    } else if (tid < NL * NQ + NL * (NQ - 1)) { // 28 threads: one sigmoid each
        const int u = tid - NL * NQ;
        const int l = u / 7, i = u - l * 7;
        const float e = __expf(-ent[l * 7 + i]);
        sWl[l][i] = __builtin_amdgcn_rcpf(1.0f + e);
    } else if (tid >= 64 && tid < 64 + NO) {    // 16 threads: bias
        sB[tid - 64] = pb[tid - 64];
    }
    __syncthreads();

    if (tid < NO) {   // FMA-only composition: W_eff = proj_w * prod_l (E_l D_l)
        float W[NQ];
        #pragma unroll
        for (int q = 0; q < NQ; ++q) W[q] = pw[tid * NQ + q];
        #pragma unroll
        for (int l = NL - 1; l >= 0; --l) {
            float WE[NQ];
            WE[0] = W[0] * (1.0f - sWl[l][0]);
            #pragma unroll
            for (int j = 1; j < NQ - 1; ++j)
                WE[j] = W[j] * (1.0f - sWl[l][j]) + W[j - 1] * sWl[l][j - 1];
            WE[NQ - 1] = W[NQ - 1] + W[NQ - 2] * sWl[l][NQ - 2];
            #pragma unroll
            for (int q = 0; q < NQ; ++q) W[q] = WE[q] * sScale[l][q];
        }
        #pragma unroll
        for (int q = 0; q < NQ; ++q) sW[tid][q] = W[q];
    }
    __syncthreads();

    // ---- tanh of my 4 values per half-row (16 total) ----
    float m[4][4];
    #pragma unroll
    for (int k = 0; k < 4; ++k) {
        #pragma unroll
        for (int j = 0; j < 4; ++j) {
            float e = __expf(2.0f * a[k][j]);
            m[k][j] = 1.0f - 2.0f * __builtin_amdgcn_rcpf(e + 1.0f);
        }
    }

    // ---- pair exchange via shfl_xor(1): build full 8-vectors ----
    float t[4][8];
    #pragma unroll
    for (int k = 0; k < 4; ++k) {
        #pragma unroll
        for (int j = 0; j < 4; ++j) {
            float o = __shfl_xor(m[k][j], 1, 64);
            t[k][j]     = h ? o : m[k][j];
            t[k][j + 4] = h ? m[k][j] : o;
        }
    }

    // ---- matvec: lane computes outputs [h*8, h*8+8) for 4 rows.
    //      Weight ds_read_b128 pairs amortized across all 4 rows. ----
    const int base = h * 8;
    const float4v* wrow = (const float4v*)&sW[base][0];
    float acc[4][8];
    #pragma unroll
    for (int j = 0; j < 8; ++j) {
        float4v w0 = wrow[2 * j];
        float4v w1 = wrow[2 * j + 1];
        float bj = sB[base + j];
        #pragma unroll
        for (int k = 0; k < 4; ++k) {
            acc[k][j] = bj
                + w0.x * t[k][0] + w0.y * t[k][1] + w0.z * t[k][2] + w0.w * t[k][3]
                + w1.x * t[k][4] + w1.y * t[k][5] + w1.z * t[k][6] + w1.w * t[k][7];
        }
    }

    // ---- nontemporal dense stores (2KB contiguous per wave-instr) ----
    #pragma unroll
    for (int k = 0; k < 4; ++k) {
        if (v[k]) {
            float4v* p = (float4v*)(out + (size_t)(g[k] >> 1) * 16 + base);
            float4v u0 = {acc[k][0], acc[k][1], acc[k][2], acc[k][3]};
            float4v u1 = {acc[k][4], acc[k][5], acc[k][6], acc[k][7]};
            __builtin_nontemporal_store(u0, p);
            __builtin_nontemporal_store(u1, p + 1);
        }
    }
}

extern "C" void kernel_launch(void* const* d_in, const int* in_sizes, int n_in,
                              void* d_out, int out_size, void* d_ws, size_t ws_size,
                              hipStream_t stream) {
    const float* x   = (const float*)d_in[0];
    const float* rot = (const float*)d_in[1];
    const float* ent = (const float*)d_in[2];
    const float* pw  = (const float*)d_in[3];
    const float* pb  = (const float*)d_in[4];
    float* out = (float*)d_out;

    const int n_rows = in_sizes[0] / 64;            // B*S = 524288
    const int nhalf = n_rows * 2;
    const int block = 256;
    // each thread covers 4 half-rows
    const int grid = (nhalf + block * 4 - 1) / (block * 4);  // 1024
    hipLaunchKernelGGL(qcl_fused, dim3(grid), dim3(block), 0, stream,
                       x, rot, ent, pw, pb, out, n_rows);
}